// Round 11
// baseline (340.134 us; speedup 1.0000x reference)
//
#include <hip/hip_runtime.h>

#define EPSF 1e-8f

constexpr int B_  = 16;
constexpr int C_  = 32;
constexpr int O_  = 32;
constexpr int HW  = 196;    // 14*14
constexpr int T9  = 9;
constexpr int PR  = 108;    // padded dwords per hw-row: 9 t * 12 (16B-aligned t-rows)
constexpr int CHR = 32;     // rows per chunk
constexpr int LDSF = CHR * PR;            // 3456 floats = 13824 B
constexpr int PW   = C_ * 2;              // partials per (b,o,t): c x z
constexpr int P1_N = B_ * O_ * T9 * PW;   // 294912
constexpr int P2_N = B_ * O_ * PW;        // 32768
constexpr int XT_N = C_ * B_ * 9 * HW;    // 903168
constexpr int PT_N = C_ * B_ * HW;        // 100352

// ---------------------------------------------------------------------------
// Kernel P: x -> xT[c][b][s][hw] (x0.1 folded), p -> pT[c][b][hw].
// Reads are fully coalesced (linear f4 over x); scatter is on the write side.
// ---------------------------------------------------------------------------
__global__ __launch_bounds__(256) void caps_pre(
    const float* __restrict__ x, const float* __restrict__ p,
    float* __restrict__ xT, float* __restrict__ pT)
{
    const int idx = blockIdx.x * 256 + threadIdx.x;
    const int stride = gridDim.x * 256;
    const float4* x4 = (const float4*)x;
    for (int i = idx; i < XT_N / 4; i += stride) {
        const float4 v = x4[i];
        const int m0 = i * 4;
#pragma unroll
        for (int k = 0; k < 4; ++k) {
            const int m  = m0 + k;         // ((b*32+c)*196 + hw)*9 + s
            const int s  = m % 9;
            const int r  = m / 9;          // (b*32+c)*196 + hw
            const int hw = r % HW;
            const int r2 = r / HW;         // b*32 + c
            const int c  = r2 % C_;
            const int b  = r2 / C_;
            xT[((size_t)(c * B_ + b) * 9 + s) * HW + hw] = 0.1f * ((const float*)&v)[k];
        }
    }
    for (int m = idx; m < PT_N; m += stride) {
        const int hw = m % HW;
        const int r2 = m / HW;             // b*32 + c
        const int c  = r2 % C_;
        const int b  = r2 / C_;
        pT[(size_t)(c * B_ + b) * HW + hw] = p[m];
    }
}

// ---------------------------------------------------------------------------
// Kernel A: block = (o, c, z). z=0 -> rows 0..95 (3 chunks of 32), z=1 ->
// rows 96..195 (3x32+4). 128 threads = 32 rows x 4 b-groups (J=4).
// Staging: ALL 6 float4 loads issued to registers first (deep in-flight
// window), then padded scatter ds_write [row][t][12] -> aligned b128 reads.
// 2048 blocks = exactly 8 blocks/CU co-resident, zero tail.
// ---------------------------------------------------------------------------
__global__ __launch_bounds__(128, 4) void caps_main(
    const float* __restrict__ T,
    const float* __restrict__ xT, const float* __restrict__ pT,
    float* __restrict__ part1,    // [b][o][t][c*2+z]
    float* __restrict__ part2s)   // [b][o][c*2+z]
{
    const int o    = blockIdx.x;
    const int c    = blockIdx.y;
    const int z    = blockIdx.z;
    const int tid  = threadIdx.x;
    const int bg   = tid >> 5;    // b-group 0..3
    const int row  = tid & 31;    // hw row within chunk

    __shared__ __align__(16) float tsh[LDSF];

    const int base   = z * 96;
    const int nrows  = z ? 100 : 96;
    const int nchunk = z ? 4 : 3;

    const float* Tb = T + (size_t)(c * O_ + o) * (HW * 81);

    const float* xbase[4];
    const float* pbase[4];
#pragma unroll
    for (int j = 0; j < 4; ++j) {
        const int b = bg * 4 + j;
        xbase[j] = xT + (size_t)(c * B_ + b) * 9 * HW;
        pbase[j] = pT + (size_t)(c * B_ + b) * HW;
    }

    float acc1[4][9], a2s[4];
#pragma unroll
    for (int j = 0; j < 4; ++j) {
        a2s[j] = 0.f;
#pragma unroll
        for (int t = 0; t < 9; ++t) acc1[j][t] = 0.f;
    }

    for (int k = 0; k < nchunk; ++k) {
        const int hw0 = base + k * CHR;
        const int rem = base + nrows - hw0;
        const int R   = rem < CHR ? rem : CHR;   // 32 or 4
        const int nf4 = (R * 81) >> 2;           // 648 or 81

        // issue ALL chunk loads before any LDS write (deep MLP window)
        const float4* g4 = (const float4*)(Tb + (size_t)hw0 * 81);
        float4 v[6];
#pragma unroll
        for (int q = 0; q < 6; ++q) {
            const int i = tid + 128 * q;
            if (i < nf4) v[q] = g4[i];
        }

        if (k) __syncthreads();   // prior chunk's reads done before overwrite

#pragma unroll
        for (int q = 0; q < 6; ++q) {
            const int i = tid + 128 * q;
            if (i < nf4) {
                const int e = 4 * i;
#pragma unroll
                for (int k2 = 0; k2 < 4; ++k2) {
                    const int e2 = e + k2;
                    tsh[e2 + 3 * (e2 / 9)] = ((const float*)&v[q])[k2];
                }
            }
        }
        __syncthreads();

        if (row < R) {
            const int hw = hw0 + row;
            float xr[4][9], pwt[4];
#pragma unroll
            for (int j = 0; j < 4; ++j) {
#pragma unroll
                for (int s = 0; s < 9; ++s) xr[j][s] = xbase[j][(size_t)s * HW + hw];
                pwt[j] = pbase[j][hw];
            }
            const float* rowb = tsh + row * PR;
#pragma unroll
            for (int t = 0; t < 9; ++t) {
                const float4 ta  = *(const float4*)(rowb + t * 12);
                const float4 tb4 = *(const float4*)(rowb + t * 12 + 4);
                const float  t8  = rowb[t * 12 + 8];
#pragma unroll
                for (int j = 0; j < 4; ++j) {
                    float pr = ta.x * xr[j][0];
                    pr = fmaf(ta.y,  xr[j][1], pr);
                    pr = fmaf(ta.z,  xr[j][2], pr);
                    pr = fmaf(ta.w,  xr[j][3], pr);
                    pr = fmaf(tb4.x, xr[j][4], pr);
                    pr = fmaf(tb4.y, xr[j][5], pr);
                    pr = fmaf(tb4.z, xr[j][6], pr);
                    pr = fmaf(tb4.w, xr[j][7], pr);
                    pr = fmaf(t8,    xr[j][8], pr);
                    const float q = pwt[j] * pr;
                    acc1[j][t] += q;
                    a2s[j] = fmaf(q, pr, a2s[j]);
                }
            }
        }
    }

    // 5-step butterfly over the 32 row-lanes (stays within each 32-half)
#pragma unroll
    for (int j = 0; j < 4; ++j) {
        const int b = bg * 4 + j;
#pragma unroll
        for (int t = 0; t < 9; ++t) {
            float v = acc1[j][t];
            v += __shfl_xor(v, 1, 64);
            v += __shfl_xor(v, 2, 64);
            v += __shfl_xor(v, 4, 64);
            v += __shfl_xor(v, 8, 64);
            v += __shfl_xor(v, 16, 64);
            if (row == 0)
                part1[((size_t)(b * O_ + o) * 9 + t) * PW + c * 2 + z] = v;
        }
        float v2 = a2s[j];
        v2 += __shfl_xor(v2, 1, 64);
        v2 += __shfl_xor(v2, 2, 64);
        v2 += __shfl_xor(v2, 4, 64);
        v2 += __shfl_xor(v2, 8, 64);
        v2 += __shfl_xor(v2, 16, 64);
        if (row == 0)
            part2s[(size_t)(b * O_ + o) * PW + c * 2 + z] = v2;
    }
}

// ---------------------------------------------------------------------------
// Kernel B: per-b finalize. psum; s1 per (o,t); caps out;
// vs = (sum_t s2 - 2*sum_t caps*s1 + psum*sum_t caps^2)/denom; p_updated.
// ---------------------------------------------------------------------------
__global__ __launch_bounds__(256) void caps_final(
    const float* __restrict__ p,
    const float* __restrict__ part1, const float* __restrict__ part2s,
    float* __restrict__ out)          // caps [B][O][9] then p_updated [B][O]
{
    const int b   = blockIdx.x;
    const int tid = threadIdx.x;

    __shared__ float w1[O_ * T9];
    __shared__ float w2[O_ * T9];
    __shared__ float red[4];
    __shared__ float s_psum;

    const float* pb = p + (size_t)b * (C_ * HW);
    float a = 0.f;
    for (int i = tid; i < C_ * HW; i += 256) a += pb[i];
#pragma unroll
    for (int m = 1; m < 64; m <<= 1) a += __shfl_xor(a, m, 64);
    if ((tid & 63) == 0) red[tid >> 6] = a;
    __syncthreads();
    if (tid == 0) s_psum = (red[0] + red[1]) + (red[2] + red[3]);
    __syncthreads();
    const float psum  = s_psum;
    const float denom = psum + EPSF;

    for (int e = tid; e < O_ * T9; e += 256) {
        const float4* q1 = (const float4*)(part1 + (size_t)(b * 288 + e) * PW);
        float s1 = 0.f;
#pragma unroll
        for (int i = 0; i < PW / 4; ++i) {
            const float4 v = q1[i];
            s1 += (v.x + v.y) + (v.z + v.w);
        }
        const float caps = s1 / denom;
        out[(size_t)b * 288 + e] = caps;
        w1[e] = caps * s1;
        w2[e] = caps * caps;
    }
    __syncthreads();

    if (tid < O_) {
        const int o = tid;
        const float4* q2 = (const float4*)(part2s + (size_t)(b * O_ + o) * PW);
        float s2 = 0.f;
#pragma unroll
        for (int i = 0; i < PW / 4; ++i) {
            const float4 v = q2[i];
            s2 += (v.x + v.y) + (v.z + v.w);
        }
        float d2 = 0.f, dc = 0.f;
#pragma unroll
        for (int t = 0; t < 9; ++t) { d2 += w1[o * 9 + t]; dc += w2[o * 9 + t]; }
        float vs = (s2 - 2.f * d2 + psum * dc) / denom;
        float mx = vs;
#pragma unroll
        for (int msk = 1; msk < 32; msk <<= 1) mx = fmaxf(mx, __shfl_xor(mx, msk, 32));
        out[(size_t)B_ * O_ * T9 + b * O_ + o] = 1.f - vs / (mx + EPSF);
    }
}

extern "C" void kernel_launch(void* const* d_in, const int* in_sizes, int n_in,
                              void* d_out, int out_size, void* d_ws, size_t ws_size,
                              hipStream_t stream)
{
    (void)in_sizes; (void)n_in; (void)out_size; (void)ws_size;
    const float* x = (const float*)d_in[0];   // (16,32,14,14,9)
    const float* p = (const float*)d_in[1];   // (16,32,14,14)
    // d_in[2] = epoch (unused)
    const float* T = (const float*)d_in[3];   // (1,32,32,14,14,9,9)
    float* out = (float*)d_out;

    float* part1  = (float*)d_ws;
    float* part2s = part1 + P1_N;
    float* xT     = part2s + P2_N;
    float* pT     = xT + XT_N;

    caps_pre<<<1024, 256, 0, stream>>>(x, p, xT, pT);
    dim3 gridA(O_, C_, 2);   // o fast; same-c blocks adjacent -> L2 reuse of xT
    caps_main<<<gridA, 128, 0, stream>>>(T, xT, pT, part1, part2s);
    caps_final<<<B_, 256, 0, stream>>>(p, part1, part2s, out);
}

// Round 12
// 82.465 us; speedup vs baseline: 4.1246x; 4.1246x over previous
//
#include <hip/hip_runtime.h>

#define EPSF 1e-8f

constexpr int B_  = 16;
constexpr int C_  = 32;
constexpr int O_  = 32;
constexpr int HW  = 196;    // 14*14
constexpr int T9  = 9;
constexpr int PR  = 108;    // padded dwords per hw-row: 9 t * 12 (16B-aligned t-rows)
constexpr int CHR = 32;     // rows per chunk
constexpr int LDSF = CHR * PR;            // 3456 floats = 13824 B
constexpr int PW   = C_ * 2;              // partials per (b,o,t): c x z
constexpr int P1_N = B_ * O_ * T9 * PW;   // 294912
constexpr int P2_N = B_ * O_ * PW;        // 32768
constexpr int XT_N = C_ * B_ * 9 * HW;    // 903168
constexpr int PT_N = C_ * B_ * HW;        // 100352

// ---------------------------------------------------------------------------
// Kernel P: x -> xT[c][b][s][hw] (x0.1 folded), p -> pT[c][b][hw].
// Reads are fully coalesced (linear f4 over x); scatter is on the write side.
// ---------------------------------------------------------------------------
__global__ __launch_bounds__(256) void caps_pre(
    const float* __restrict__ x, const float* __restrict__ p,
    float* __restrict__ xT, float* __restrict__ pT)
{
    const int idx = blockIdx.x * 256 + threadIdx.x;
    const int stride = gridDim.x * 256;
    const float4* x4 = (const float4*)x;
    for (int i = idx; i < XT_N / 4; i += stride) {
        const float4 v = x4[i];
        const int m0 = i * 4;
#pragma unroll
        for (int k = 0; k < 4; ++k) {
            const int m  = m0 + k;         // ((b*32+c)*196 + hw)*9 + s
            const int s  = m % 9;
            const int r  = m / 9;          // (b*32+c)*196 + hw
            const int hw = r % HW;
            const int r2 = r / HW;         // b*32 + c
            const int c  = r2 % C_;
            const int b  = r2 / C_;
            xT[((size_t)(c * B_ + b) * 9 + s) * HW + hw] = 0.1f * ((const float*)&v)[k];
        }
    }
    for (int m = idx; m < PT_N; m += stride) {
        const int hw = m % HW;
        const int r2 = m / HW;             // b*32 + c
        const int c  = r2 % C_;
        const int b  = r2 / C_;
        pT[(size_t)(c * B_ + b) * HW + hw] = p[m];
    }
}

// ---------------------------------------------------------------------------
// Kernel A: block = (o, c, z). z=0 -> rows 0..95 (3 chunks of 32), z=1 ->
// rows 96..195 (3x32+4). 128 threads = 32 rows x 4 b-groups (J=4).
// Staging: ALL 6 float4 loads issued to registers first (deep in-flight
// window), then padded scatter ds_write [row][t][12] -> aligned b128 reads.
// NO min-waves launch_bounds arg: round-11's (128,4) made hipcc clamp to
// 64 VGPRs and spill v[]/xr[] to scratch (WRITE_SIZE 583 MB, dur 340 us).
// ---------------------------------------------------------------------------
__global__ __launch_bounds__(128) void caps_main(
    const float* __restrict__ T,
    const float* __restrict__ xT, const float* __restrict__ pT,
    float* __restrict__ part1,    // [b][o][t][c*2+z]
    float* __restrict__ part2s)   // [b][o][c*2+z]
{
    const int o    = blockIdx.x;
    const int c    = blockIdx.y;
    const int z    = blockIdx.z;
    const int tid  = threadIdx.x;
    const int bg   = tid >> 5;    // b-group 0..3
    const int row  = tid & 31;    // hw row within chunk

    __shared__ __align__(16) float tsh[LDSF];

    const int base   = z * 96;
    const int nrows  = z ? 100 : 96;
    const int nchunk = z ? 4 : 3;

    const float* Tb = T + (size_t)(c * O_ + o) * (HW * 81);

    const float* xbase[4];
    const float* pbase[4];
#pragma unroll
    for (int j = 0; j < 4; ++j) {
        const int b = bg * 4 + j;
        xbase[j] = xT + (size_t)(c * B_ + b) * 9 * HW;
        pbase[j] = pT + (size_t)(c * B_ + b) * HW;
    }

    float acc1[4][9], a2s[4];
#pragma unroll
    for (int j = 0; j < 4; ++j) {
        a2s[j] = 0.f;
#pragma unroll
        for (int t = 0; t < 9; ++t) acc1[j][t] = 0.f;
    }

    for (int k = 0; k < nchunk; ++k) {
        const int hw0 = base + k * CHR;
        const int rem = base + nrows - hw0;
        const int R   = rem < CHR ? rem : CHR;   // 32 or 4
        const int nf4 = (R * 81) >> 2;           // 648 or 81

        // issue ALL chunk loads before any LDS write (deep MLP window)
        const float4* g4 = (const float4*)(Tb + (size_t)hw0 * 81);
        float4 v[6];
#pragma unroll
        for (int q = 0; q < 6; ++q) {
            const int i = tid + 128 * q;
            if (i < nf4) v[q] = g4[i];
        }

        if (k) __syncthreads();   // prior chunk's reads done before overwrite

#pragma unroll
        for (int q = 0; q < 6; ++q) {
            const int i = tid + 128 * q;
            if (i < nf4) {
                const int e = 4 * i;
#pragma unroll
                for (int k2 = 0; k2 < 4; ++k2) {
                    const int e2 = e + k2;
                    tsh[e2 + 3 * (e2 / 9)] = ((const float*)&v[q])[k2];
                }
            }
        }
        __syncthreads();

        if (row < R) {
            const int hw = hw0 + row;
            float xr[4][9], pwt[4];
#pragma unroll
            for (int j = 0; j < 4; ++j) {
#pragma unroll
                for (int s = 0; s < 9; ++s) xr[j][s] = xbase[j][(size_t)s * HW + hw];
                pwt[j] = pbase[j][hw];
            }
            const float* rowb = tsh + row * PR;
#pragma unroll
            for (int t = 0; t < 9; ++t) {
                const float4 ta  = *(const float4*)(rowb + t * 12);
                const float4 tb4 = *(const float4*)(rowb + t * 12 + 4);
                const float  t8  = rowb[t * 12 + 8];
#pragma unroll
                for (int j = 0; j < 4; ++j) {
                    float pr = ta.x * xr[j][0];
                    pr = fmaf(ta.y,  xr[j][1], pr);
                    pr = fmaf(ta.z,  xr[j][2], pr);
                    pr = fmaf(ta.w,  xr[j][3], pr);
                    pr = fmaf(tb4.x, xr[j][4], pr);
                    pr = fmaf(tb4.y, xr[j][5], pr);
                    pr = fmaf(tb4.z, xr[j][6], pr);
                    pr = fmaf(tb4.w, xr[j][7], pr);
                    pr = fmaf(t8,    xr[j][8], pr);
                    const float q = pwt[j] * pr;
                    acc1[j][t] += q;
                    a2s[j] = fmaf(q, pr, a2s[j]);
                }
            }
        }
    }

    // 5-step butterfly over the 32 row-lanes (stays within each 32-half)
#pragma unroll
    for (int j = 0; j < 4; ++j) {
        const int b = bg * 4 + j;
#pragma unroll
        for (int t = 0; t < 9; ++t) {
            float v = acc1[j][t];
            v += __shfl_xor(v, 1, 64);
            v += __shfl_xor(v, 2, 64);
            v += __shfl_xor(v, 4, 64);
            v += __shfl_xor(v, 8, 64);
            v += __shfl_xor(v, 16, 64);
            if (row == 0)
                part1[((size_t)(b * O_ + o) * 9 + t) * PW + c * 2 + z] = v;
        }
        float v2 = a2s[j];
        v2 += __shfl_xor(v2, 1, 64);
        v2 += __shfl_xor(v2, 2, 64);
        v2 += __shfl_xor(v2, 4, 64);
        v2 += __shfl_xor(v2, 8, 64);
        v2 += __shfl_xor(v2, 16, 64);
        if (row == 0)
            part2s[(size_t)(b * O_ + o) * PW + c * 2 + z] = v2;
    }
}

// ---------------------------------------------------------------------------
// Kernel B: per-b finalize. psum; s1 per (o,t); caps out;
// vs = (sum_t s2 - 2*sum_t caps*s1 + psum*sum_t caps^2)/denom; p_updated.
// ---------------------------------------------------------------------------
__global__ __launch_bounds__(256) void caps_final(
    const float* __restrict__ p,
    const float* __restrict__ part1, const float* __restrict__ part2s,
    float* __restrict__ out)          // caps [B][O][9] then p_updated [B][O]
{
    const int b   = blockIdx.x;
    const int tid = threadIdx.x;

    __shared__ float w1[O_ * T9];
    __shared__ float w2[O_ * T9];
    __shared__ float red[4];
    __shared__ float s_psum;

    const float* pb = p + (size_t)b * (C_ * HW);
    float a = 0.f;
    for (int i = tid; i < C_ * HW; i += 256) a += pb[i];
#pragma unroll
    for (int m = 1; m < 64; m <<= 1) a += __shfl_xor(a, m, 64);
    if ((tid & 63) == 0) red[tid >> 6] = a;
    __syncthreads();
    if (tid == 0) s_psum = (red[0] + red[1]) + (red[2] + red[3]);
    __syncthreads();
    const float psum  = s_psum;
    const float denom = psum + EPSF;

    for (int e = tid; e < O_ * T9; e += 256) {
        const float4* q1 = (const float4*)(part1 + (size_t)(b * 288 + e) * PW);
        float s1 = 0.f;
#pragma unroll
        for (int i = 0; i < PW / 4; ++i) {
            const float4 v = q1[i];
            s1 += (v.x + v.y) + (v.z + v.w);
        }
        const float caps = s1 / denom;
        out[(size_t)b * 288 + e] = caps;
        w1[e] = caps * s1;
        w2[e] = caps * caps;
    }
    __syncthreads();

    if (tid < O_) {
        const int o = tid;
        const float4* q2 = (const float4*)(part2s + (size_t)(b * O_ + o) * PW);
        float s2 = 0.f;
#pragma unroll
        for (int i = 0; i < PW / 4; ++i) {
            const float4 v = q2[i];
            s2 += (v.x + v.y) + (v.z + v.w);
        }
        float d2 = 0.f, dc = 0.f;
#pragma unroll
        for (int t = 0; t < 9; ++t) { d2 += w1[o * 9 + t]; dc += w2[o * 9 + t]; }
        float vs = (s2 - 2.f * d2 + psum * dc) / denom;
        float mx = vs;
#pragma unroll
        for (int msk = 1; msk < 32; msk <<= 1) mx = fmaxf(mx, __shfl_xor(mx, msk, 32));
        out[(size_t)B_ * O_ * T9 + b * O_ + o] = 1.f - vs / (mx + EPSF);
    }
}

extern "C" void kernel_launch(void* const* d_in, const int* in_sizes, int n_in,
                              void* d_out, int out_size, void* d_ws, size_t ws_size,
                              hipStream_t stream)
{
    (void)in_sizes; (void)n_in; (void)out_size; (void)ws_size;
    const float* x = (const float*)d_in[0];   // (16,32,14,14,9)
    const float* p = (const float*)d_in[1];   // (16,32,14,14)
    // d_in[2] = epoch (unused)
    const float* T = (const float*)d_in[3];   // (1,32,32,14,14,9,9)
    float* out = (float*)d_out;

    float* part1  = (float*)d_ws;
    float* part2s = part1 + P1_N;
    float* xT     = part2s + P2_N;
    float* pT     = xT + XT_N;

    caps_pre<<<1024, 256, 0, stream>>>(x, p, xT, pT);
    dim3 gridA(O_, C_, 2);   // o fast; same-c blocks adjacent -> L2 reuse of xT
    caps_main<<<gridA, 128, 0, stream>>>(T, xT, pT, part1, part2s);
    caps_final<<<B_, 256, 0, stream>>>(p, part1, part2s, out);
}